// Round 5
// baseline (479.528 us; speedup 1.0000x reference)
//
#include <hip/hip_runtime.h>
#include <cstdint>
#include <cstddef>

typedef unsigned short u16;
typedef __attribute__((ext_vector_type(4))) float floatx4;
typedef __attribute__((ext_vector_type(8))) __bf16 bf16x8;

// ---------- bf16 helpers ----------
__device__ __forceinline__ float u2f(u16 u) {
    union { unsigned int i; float f; } x;
    x.i = ((unsigned int)u) << 16;
    return x.f;
}
__device__ __forceinline__ u16 f2u(float f) {
    union { float f; unsigned int i; } x;
    x.f = f;
    unsigned int r = x.i + 0x7fffu + ((x.i >> 16) & 1u);   // RNE
    return (u16)(r >> 16);
}

// ---------- transpose tile helper: in (K x N) f32 -> out (N x K) bf16 ----------
__device__ __forceinline__ void tr_tile(const float* __restrict__ in, u16* __restrict__ out,
                                        int K, int N, int bx, int by, float* tile /*32x33*/) {
    int n0 = bx * 32, k0 = by * 32;
    int tx = threadIdx.x & 31, ty = threadIdx.x >> 5;   // ty 0..7
#pragma unroll
    for (int j = 0; j < 4; ++j) {
        int r = ty + j * 8;
        tile[r * 33 + tx] = in[(size_t)(k0 + r) * N + n0 + tx];
    }
    __syncthreads();
#pragma unroll
    for (int j = 0; j < 4; ++j) {
        int r = ty + j * 8;
        out[(size_t)(n0 + r) * K + k0 + tx] = f2u(tile[tx * 33 + r]);
    }
}

__global__ __launch_bounds__(256) void transpose2_kernel(const float* __restrict__ W_in,
                                                         u16* __restrict__ Wt_in,
                                                         const float* __restrict__ Wd,
                                                         u16* __restrict__ Wt_d) {
    __shared__ float tile[32 * 33];
    int blk = blockIdx.x;
    if (blk < 4096) {
        tr_tile(W_in, Wt_in, 1024, 4096, blk & 127, blk >> 7, tile);
    } else {
        int b2 = blk - 4096;
        tr_tile(Wd, Wt_d, 2048, 2048, b2 & 63, b2 >> 6, tile);
    }
}

__global__ __launch_bounds__(256) void transpose1_kernel(const float* __restrict__ in,
                                                         u16* __restrict__ out, int K, int N) {
    __shared__ float tile[32 * 33];
    tr_tile(in, out, K, N, blockIdx.x, blockIdx.y, tile);
}

// ---------- layernorm over D=1024 + residual pre-copy (out = x) ----------
__global__ __launch_bounds__(256) void ln_kernel(const float* __restrict__ x,
                                                 const float* __restrict__ gamma,
                                                 const float* __restrict__ beta,
                                                 u16* __restrict__ h,
                                                 float* __restrict__ out) {
    int r = blockIdx.x, t = threadIdx.x;
    const float4* xr = (const float4*)(x + (size_t)r * 1024);
    float4 xv = xr[t];
    ((float4*)(out + (size_t)r * 1024))[t] = xv;   // residual base for final atomic GEMM
    float s = xv.x + xv.y + xv.z + xv.w;
    float ss = xv.x * xv.x + xv.y * xv.y + xv.z * xv.z + xv.w * xv.w;
#pragma unroll
    for (int off = 32; off > 0; off >>= 1) {
        s += __shfl_down(s, off, 64);
        ss += __shfl_down(ss, off, 64);
    }
    __shared__ float rs[4], rss[4];
    __shared__ float mu_s, ri_s;
    int wave = t >> 6, lane = t & 63;
    if (lane == 0) { rs[wave] = s; rss[wave] = ss; }
    __syncthreads();
    if (t == 0) {
        float S = rs[0] + rs[1] + rs[2] + rs[3];
        float SS = rss[0] + rss[1] + rss[2] + rss[3];
        float mu = S * (1.f / 1024.f);
        float var = SS * (1.f / 1024.f) - mu * mu;
        mu_s = mu;
        ri_s = rsqrtf(fmaxf(var, 0.f) + 1e-5f);
    }
    __syncthreads();
    float mu = mu_s, ri = ri_s;
    float4 gv = ((const float4*)gamma)[t];
    float4 bv = ((const float4*)beta)[t];
    ushort4 o;
    o.x = f2u((xv.x - mu) * ri * gv.x + bv.x);
    o.y = f2u((xv.y - mu) * ri * gv.y + bv.y);
    o.z = f2u((xv.z - mu) * ri * gv.z + bv.z);
    o.w = f2u((xv.w - mu) * ri * gv.w + bv.w);
    ((ushort4*)(h + (size_t)r * 1024))[t] = o;
}

__device__ __forceinline__ void gl_lds16(const u16* g, u16* l) {
    __builtin_amdgcn_global_load_lds(
        (const __attribute__((address_space(1))) void*)g,
        (__attribute__((address_space(3))) void*)l, 16, 0, 0);
}

// ---------- GEMM1: 128x128 tile, BK=64, 4 waves x (4x4) — m97 structure ----------
__global__ __launch_bounds__(256)
void gemm_k(const u16* __restrict__ A, const u16* __restrict__ Bt,
            u16* __restrict__ out, int M, int N, int K) {
    __shared__ u16 As[128 * 64];
    __shared__ u16 Bs[128 * 64];
    const int tid = threadIdx.x;
    const int wave = tid >> 6, lane = tid & 63;
    const int row0 = blockIdx.y * 128, col0 = blockIdx.x * 128;
    const int l16 = lane & 15, q = lane >> 4;
    const int sRow = lane >> 2, sK = (lane & 3) * 8;

    floatx4 acc[4][4];
#pragma unroll
    for (int i = 0; i < 4; ++i)
#pragma unroll
        for (int j = 0; j < 4; ++j) acc[i][j] = (floatx4){0.f, 0.f, 0.f, 0.f};

    const u16* gA = A + (size_t)(row0 + wave * 32 + sRow) * K + sK;
    const u16* gB = Bt + (size_t)(col0 + wave * 32 + sRow) * K + sK;
    u16* lA = As + wave * 1024;
    u16* lB = Bs + wave * 1024;
    const int rowb = (wave >> 1) * 64, colb = (wave & 1) * 64;

    for (int k0 = 0; k0 < K; k0 += 64) {
#pragma unroll
        for (int h = 0; h < 2; ++h) {
            gl_lds16(gA + h * 32, lA + h * 4096);
            gl_lds16(gA + (size_t)16 * K + h * 32, lA + h * 4096 + 512);
            gl_lds16(gB + h * 32, lB + h * 4096);
            gl_lds16(gB + (size_t)16 * K + h * 32, lB + h * 4096 + 512);
        }
        gA += 64; gB += 64;
        __syncthreads();
#pragma unroll
        for (int h = 0; h < 2; ++h) {
            bf16x8 af[4], bfr[4];
#pragma unroll
            for (int mi = 0; mi < 4; ++mi)
                af[mi] = *(const bf16x8*)(As + h * 4096 + (rowb + mi * 16 + l16) * 32 + q * 8);
#pragma unroll
            for (int ni = 0; ni < 4; ++ni)
                bfr[ni] = *(const bf16x8*)(Bs + h * 4096 + (colb + ni * 16 + l16) * 32 + q * 8);
#pragma unroll
            for (int mi = 0; mi < 4; ++mi)
#pragma unroll
                for (int ni = 0; ni < 4; ++ni)
                    acc[mi][ni] = __builtin_amdgcn_mfma_f32_16x16x32_bf16(
                        af[mi], bfr[ni], acc[mi][ni], 0, 0, 0);
        }
        __syncthreads();
    }
    const int mB = row0 + rowb, nB = col0 + colb + l16;
#pragma unroll
    for (int mi = 0; mi < 4; ++mi)
#pragma unroll
        for (int ni = 0; ni < 4; ++ni)
#pragma unroll
            for (int rr = 0; rr < 4; ++rr)
                out[(size_t)(mB + mi * 16 + q * 4 + rr) * N + nB + ni * 16] =
                    f2u(acc[mi][ni][rr]);
}

// ---------- GEMM with in-block K-split: tile 128x64, waves = 2 spatial x 2 K-halves ----------
// Each wave: full 64x64 (4x4) accumulator over its K-half -> 8 ds_read : 16 MFMA.
// EPI 1: atomicAdd per-row sum of softplus(acc + biasf32[col]) into (float*)out
// EPI 4: atomicAdd acc into (float*)out (residual pre-initialized)
template <int EPI>
__global__ __launch_bounds__(256)
void gemm_s(const u16* __restrict__ A, const u16* __restrict__ Bt,
            void* __restrict__ out, const void* __restrict__ aux,
            int M, int N, int K, int Ksub) {
    __shared__ char smem[32768];
    u16* As = (u16*)smem;              // [2][128*32] per K-half, 16 KB
    u16* Bs = (u16*)(smem + 16384);    // [2][64*32], 8 KB
    float* accex = (float*)smem;       // [2][64*64] exchange, 32 KB (staging dead)

    const int tid = threadIdx.x;
    const int wave = tid >> 6, lane = tid & 63;
    const int s = wave & 1, p = wave >> 1;
    const int row0 = blockIdx.y * 128, col0 = blockIdx.x * 64;
    const int Khalf = Ksub >> 1;
    const int koff = blockIdx.z * Ksub + p * Khalf;
    const int l16 = lane & 15, q = lane >> 4;
    const int sRow = lane >> 2, sK = (lane & 3) * 8;

    floatx4 acc[4][4];
#pragma unroll
    for (int i = 0; i < 4; ++i)
#pragma unroll
        for (int j = 0; j < 4; ++j) acc[i][j] = (floatx4){0.f, 0.f, 0.f, 0.f};

    const u16* gA = A + (size_t)(row0 + s * 64 + sRow) * K + koff + sK;
    const u16* gB = Bt + (size_t)(col0 + s * 32 + sRow) * K + koff + sK;
    u16* lA = As + p * 4096 + s * 64 * 32;    // u16 units
    u16* lB = Bs + p * 2048 + s * 32 * 32;

    for (int k0 = 0; k0 < Khalf; k0 += 32) {
#pragma unroll
        for (int j = 0; j < 4; ++j)
            gl_lds16(gA + (size_t)(j * 16) * K, lA + j * 512);
#pragma unroll
        for (int j = 0; j < 2; ++j)
            gl_lds16(gB + (size_t)(j * 16) * K, lB + j * 512);
        gA += 32; gB += 32;
        __syncthreads();
        bf16x8 af[4], bfr[4];
#pragma unroll
        for (int mi = 0; mi < 4; ++mi)
            af[mi] = *(const bf16x8*)(As + p * 4096 + (s * 64 + mi * 16 + l16) * 32 + q * 8);
#pragma unroll
        for (int ni = 0; ni < 4; ++ni)
            bfr[ni] = *(const bf16x8*)(Bs + p * 2048 + (ni * 16 + l16) * 32 + q * 8);
#pragma unroll
        for (int mi = 0; mi < 4; ++mi)
#pragma unroll
            for (int ni = 0; ni < 4; ++ni)
                acc[mi][ni] = __builtin_amdgcn_mfma_f32_16x16x32_bf16(
                    af[mi], bfr[ni], acc[mi][ni], 0, 0, 0);
        __syncthreads();
    }

    // combine K-halves through LDS
    if (p == 1) {
#pragma unroll
        for (int mi = 0; mi < 4; ++mi)
#pragma unroll
            for (int ni = 0; ni < 4; ++ni)
#pragma unroll
                for (int rr = 0; rr < 4; ++rr)
                    accex[s * 4096 + (mi * 16 + q * 4 + rr) * 64 + ni * 16 + l16] =
                        acc[mi][ni][rr];
    }
    __syncthreads();
    if (p == 0) {
#pragma unroll
        for (int mi = 0; mi < 4; ++mi)
#pragma unroll
            for (int ni = 0; ni < 4; ++ni)
#pragma unroll
                for (int rr = 0; rr < 4; ++rr)
                    acc[mi][ni][rr] +=
                        accex[s * 4096 + (mi * 16 + q * 4 + rr) * 64 + ni * 16 + l16];

        const int mB = row0 + s * 64;
        const int nB = col0 + l16;
        if constexpr (EPI == 1) {
            float* dacc = (float*)out;
            const float* bias = (const float*)aux;
#pragma unroll
            for (int mi = 0; mi < 4; ++mi) {
#pragma unroll
                for (int rr = 0; rr < 4; ++rr) {
                    float sv = 0.f;
#pragma unroll
                    for (int ni = 0; ni < 4; ++ni) {
                        float t2 = acc[mi][ni][rr] + bias[nB + ni * 16];
                        sv += (t2 > 20.f) ? t2 : log1pf(expf(t2));
                    }
#pragma unroll
                    for (int off = 1; off < 16; off <<= 1)
                        sv += __shfl_xor(sv, off, 64);
                    if (l16 == 0)
                        atomicAdd(&dacc[mB + mi * 16 + q * 4 + rr], sv);
                }
            }
        } else {
            float* C = (float*)out;
#pragma unroll
            for (int mi = 0; mi < 4; ++mi)
#pragma unroll
                for (int ni = 0; ni < 4; ++ni)
#pragma unroll
                    for (int rr = 0; rr < 4; ++rr)
                        atomicAdd(&C[(size_t)(mB + mi * 16 + q * 4 + rr) * N + nB + ni * 16],
                                  acc[mi][ni][rr]);
        }
    }
}

// ---------- depthwise causal conv(K=4) + SiLU, vectorized x8 ----------
__global__ __launch_bounds__(256) void conv_silu_kernel(const u16* __restrict__ xg,
                                                        const float* __restrict__ conv_w,
                                                        const float* __restrict__ conv_b,
                                                        u16* __restrict__ xsc) {
    int r = blockIdx.x;                       // 0..4095
    int l = r & 2047, bb = r >> 11;
    int t = threadIdx.x, d8 = t * 8;
    float xs[8];
    {
        float4 b0 = *(const float4*)(conv_b + d8);
        float4 b1 = *(const float4*)(conv_b + d8 + 4);
        xs[0] = b0.x; xs[1] = b0.y; xs[2] = b0.z; xs[3] = b0.w;
        xs[4] = b1.x; xs[5] = b1.y; xs[6] = b1.z; xs[7] = b1.w;
    }
    float w[8][4];
#pragma unroll
    for (int j = 0; j < 8; ++j) {
        float4 wv = *(const float4*)(conv_w + (size_t)(d8 + j) * 4);
        w[j][0] = wv.x; w[j][1] = wv.y; w[j][2] = wv.z; w[j][3] = wv.w;
    }
#pragma unroll
    for (int k = 0; k < 4; ++k) {
        int ls = l + k - 3;
        if (ls >= 0) {
            const u16* row = xg + (size_t)((bb << 11) + ls) * 4096 + d8;
            ushort4 u0 = *(const ushort4*)row;
            ushort4 u1 = *(const ushort4*)(row + 4);
            xs[0] += w[0][k] * u2f(u0.x); xs[1] += w[1][k] * u2f(u0.y);
            xs[2] += w[2][k] * u2f(u0.z); xs[3] += w[3][k] * u2f(u0.w);
            xs[4] += w[4][k] * u2f(u1.x); xs[5] += w[5][k] * u2f(u1.y);
            xs[6] += w[6][k] * u2f(u1.z); xs[7] += w[7][k] * u2f(u1.w);
        }
    }
    ushort4 o0, o1;
#pragma unroll
    for (int j = 0; j < 8; ++j) xs[j] = xs[j] / (1.f + expf(-xs[j]));
    o0.x = f2u(xs[0]); o0.y = f2u(xs[1]); o0.z = f2u(xs[2]); o0.w = f2u(xs[3]);
    o1.x = f2u(xs[4]); o1.y = f2u(xs[5]); o1.z = f2u(xs[6]); o1.w = f2u(xs[7]);
    *(ushort4*)(xsc + (size_t)r * 2048 + d8) = o0;
    *(ushort4*)(xsc + (size_t)r * 2048 + d8 + 4) = o1;
}

// ---------- Bdot[n][r] = <xsc[r,:], B_mat[n,:]> (n-major out) ----------
__global__ __launch_bounds__(256) void bdot_kernel(const u16* __restrict__ xsc,
                                                   const float* __restrict__ B_mat,
                                                   float* __restrict__ Bdotn) {
    int r = blockIdx.x, t = threadIdx.x, d8 = t * 8;
    int wave = t >> 6, lane = t & 63;
    const u16* xr = xsc + (size_t)r * 2048 + d8;
    ushort4 u0 = *(const ushort4*)xr;
    ushort4 u1 = *(const ushort4*)(xr + 4);
    float xs[8] = {u2f(u0.x), u2f(u0.y), u2f(u0.z), u2f(u0.w),
                   u2f(u1.x), u2f(u1.y), u2f(u1.z), u2f(u1.w)};
    __shared__ float part[4 * 16];
#pragma unroll
    for (int n = 0; n < 16; ++n) {
        const float* br = B_mat + (size_t)n * 2048 + d8;
        float4 c0 = *(const float4*)br;
        float4 c1 = *(const float4*)(br + 4);
        float a = xs[0] * c0.x + xs[1] * c0.y + xs[2] * c0.z + xs[3] * c0.w
                + xs[4] * c1.x + xs[5] * c1.y + xs[6] * c1.z + xs[7] * c1.w;
#pragma unroll
        for (int off = 1; off < 64; off <<= 1)
            a += __shfl_xor(a, off, 64);
        if (lane == 0) part[wave * 16 + n] = a;
    }
    __syncthreads();
    if (t < 16)
        Bdotn[(size_t)t * 4096 + r] = part[t] + part[16 + t] + part[32 + t] + part[48 + t];
}

// ---------- selective scan: 32 chains, 1 wave each; n-major I/O, LDS-coalesced ----------
__global__ __launch_bounds__(64) void scan_kernel(const float* __restrict__ delta_acc,
                                                  const float* __restrict__ Bdotn,
                                                  const float* __restrict__ A_log,
                                                  float* __restrict__ hsn) {
    int chain = blockIdx.x;                 // 0..31
    int b = chain >> 4, n = chain & 15;
    int j = threadIdx.x;                    // 0..63
    __shared__ float sd[2048], sb[2048];
    // coalesced stage-in
#pragma unroll
    for (int m = 0; m < 8; ++m) {
        int idx = (m * 64 + j) * 4;
        *(float4*)(sd + idx) = *(const float4*)(delta_acc + b * 2048 + idx);
        *(float4*)(sb + idx) = *(const float4*)(Bdotn + (size_t)n * 4096 + b * 2048 + idx);
    }
    __syncthreads();
    float An = -expf(A_log[n]);
    float a[32], bb[32];
#pragma unroll
    for (int i = 0; i < 32; ++i) {
        float dl = sd[j * 32 + i] * (1.f / 2048.f);
        a[i] = expf(dl * An);
        bb[i] = sb[j * 32 + i] * dl;
    }
    float Aacc = 1.f, Bacc = 0.f;
#pragma unroll
    for (int i = 0; i < 32; ++i) {
        Bacc = a[i] * Bacc + bb[i];
        Aacc = a[i] * Aacc;
    }
#pragma unroll
    for (int d = 1; d < 64; d <<= 1) {
        float Ap = __shfl_up(Aacc, d, 64);
        float Bp = __shfl_up(Bacc, d, 64);
        if (j >= d) {
            Bacc = Aacc * Bp + Bacc;
            Aacc = Aacc * Ap;
        }
    }
    float hstart = __shfl_up(Bacc, 1, 64);
    if (j == 0) hstart = 0.f;
    float h = hstart;
    __syncthreads();
#pragma unroll
    for (int i = 0; i < 32; ++i) {
        h = a[i] * h + bb[i];
        sd[j * 32 + i] = h;   // reuse sd as output staging
    }
    __syncthreads();
#pragma unroll
    for (int m = 0; m < 8; ++m) {
        int idx = (m * 64 + j) * 4;
        *(float4*)(hsn + (size_t)n * 4096 + b * 2048 + idx) = *(const float4*)(sd + idx);
    }
}

// ---------- ymid = (hs·C_mat[d,:] + D_vec*xsc) * silu(gate), bf16 out ----------
__global__ __launch_bounds__(256) void ymid_kernel(const float* __restrict__ hsn,
                                                   const float* __restrict__ C_mat,
                                                   const float* __restrict__ D_vec,
                                                   const u16* __restrict__ xsc,
                                                   const u16* __restrict__ xg,
                                                   u16* __restrict__ ymid) {
    int r = blockIdx.y;
    int d = blockIdx.x * 256 + threadIdx.x;
    __shared__ float hsv[16];
    if (threadIdx.x < 16) hsv[threadIdx.x] = hsn[(size_t)threadIdx.x * 4096 + r];
    __syncthreads();
    const float* crow = C_mat + (size_t)d * 16;
    float acc = 0.f;
#pragma unroll
    for (int n = 0; n < 16; ++n) acc += hsv[n] * crow[n];
    float xv = u2f(xsc[(size_t)r * 2048 + d]);
    float g = u2f(xg[(size_t)r * 4096 + 2048 + d]);
    float y = acc + D_vec[d] * xv;
    y *= g / (1.f + expf(-g));
    ymid[(size_t)r * 2048 + d] = f2u(y);
}

extern "C" void kernel_launch(void* const* d_in, const int* in_sizes, int n_in,
                              void* d_out, int out_size, void* d_ws, size_t ws_size,
                              hipStream_t stream) {
    (void)in_sizes; (void)n_in;
    const float* x      = (const float*)d_in[0];
    const float* ln_g   = (const float*)d_in[1];
    const float* ln_b   = (const float*)d_in[2];
    const float* W_in   = (const float*)d_in[3];
    const float* conv_w = (const float*)d_in[4];
    const float* conv_b = (const float*)d_in[5];
    const float* A_log  = (const float*)d_in[6];
    const float* B_mat  = (const float*)d_in[7];
    const float* C_mat  = (const float*)d_in[8];
    const float* D_vec  = (const float*)d_in[9];
    const float* Wd     = (const float*)d_in[10];
    const float* bd     = (const float*)d_in[11];
    const float* W_out  = (const float*)d_in[12];
    float* out = (float*)d_out;

    // ---- workspace layout (time-overlaid), ~73 MiB ----
    char* base = (char*)d_ws;
    u16* Wt_in  = (u16*)base;                          // 4096x1024 bf16
    u16* h_ln   = (u16*)base + 4096ull * 1024;         // 4096x1024 bf16
    u16* ymid   = (u16*)base;                          // 4096x2048 bf16 (reuse bufA)
    u16* Wt_d   = (u16*)(base + (16ull << 20));        // 2048x2048 bf16
    u16* Wt_out = (u16*)(base + (16ull << 20));        // 1024x2048 bf16 (reuse bufB)
    u16* xg     = (u16*)(base + (24ull << 20));        // 4096x4096 bf16 (32 MiB)
    u16* xsc    = (u16*)(base + (56ull << 20));        // 4096x2048 bf16 (16 MiB)
    float* delta_acc = (float*)(base + (72ull << 20)); // 4096 f32
    float* Bdotn = delta_acc + 4096;                   // [16][4096] f32
    float* hsn   = Bdotn + 16 * 4096;                  // [16][4096] f32
    size_t needed = (72ull << 20) + 4096ull * 4 * (1 + 2 * 16);

    if (needed > ws_size) {
        hipMemsetAsync(d_out, 0x7F, (size_t)out_size * 4, stream);  // finite sentinel
        return;
    }

    // 1. W_in^T + Wd^T ; layernorm (+ out=x) ; zero delta accumulator
    transpose2_kernel<<<8192, 256, 0, stream>>>(W_in, Wt_in, Wd, Wt_d);
    ln_kernel<<<4096, 256, 0, stream>>>(x, ln_g, ln_b, h_ln, out);
    hipMemsetAsync(delta_acc, 0, 4096 * sizeof(float), stream);
    // 2. xg = h @ W_in   128x128 tile, grid 1024
    gemm_k<<<dim3(32, 32), 256, 0, stream>>>(h_ln, Wt_in, xg, 4096, 4096, 1024);
    // 3. conv + silu
    conv_silu_kernel<<<4096, 256, 0, stream>>>(xg, conv_w, conv_b, xsc);
    // 4. Bdot (n-major)
    bdot_kernel<<<4096, 256, 0, stream>>>(xsc, B_mat, Bdotn);
    // 5. delta GEMM: in-block K-split 128x64, grid (32,32) = 1024
    gemm_s<1><<<dim3(32, 32, 1), 256, 0, stream>>>(xsc, Wt_d, delta_acc, bd,
                                                   4096, 2048, 2048, 2048);
    // 6. W_out^T (bufB, Wt_d dead)
    transpose1_kernel<<<dim3(32, 64), 256, 0, stream>>>(W_out, Wt_out, 2048, 1024);
    // 7. selective scan
    scan_kernel<<<32, 64, 0, stream>>>(delta_acc, Bdotn, A_log, hsn);
    // 8. ymid (into bufA)
    ymid_kernel<<<dim3(8, 4096), 256, 0, stream>>>(hsn, C_mat, D_vec, xsc, xg, ymid);
    // 9. out += ymid @ W_out : in-block split + global split-K=2, grid (16,32,2) = 1024
    gemm_s<4><<<dim3(16, 32, 2), 256, 0, stream>>>(ymid, Wt_out, out, nullptr,
                                                   4096, 1024, 2048, 1024);
}

// Round 6
// 388.971 us; speedup vs baseline: 1.2328x; 1.2328x over previous
//
#include <hip/hip_runtime.h>
#include <cstdint>
#include <cstddef>

typedef unsigned short u16;
typedef __attribute__((ext_vector_type(4))) float floatx4;
typedef __attribute__((ext_vector_type(8))) __bf16 bf16x8;

// ---------- bf16 helpers ----------
__device__ __forceinline__ float u2f(u16 u) {
    union { unsigned int i; float f; } x;
    x.i = ((unsigned int)u) << 16;
    return x.f;
}
__device__ __forceinline__ u16 f2u(float f) {
    union { float f; unsigned int i; } x;
    x.f = f;
    unsigned int r = x.i + 0x7fffu + ((x.i >> 16) & 1u);   // RNE
    return (u16)(r >> 16);
}

// ---------- merged weight transpose: (K x N) f32 -> (N x K) bf16, 3 weights ----------
__device__ __forceinline__ void tr_tile(const float* __restrict__ in, u16* __restrict__ out,
                                        int K, int N, int bx, int by, float* tile /*32x33*/) {
    int n0 = bx * 32, k0 = by * 32;
    int tx = threadIdx.x & 31, ty = threadIdx.x >> 5;   // ty 0..7
#pragma unroll
    for (int j = 0; j < 4; ++j) {
        int r = ty + j * 8;
        tile[r * 33 + tx] = in[(size_t)(k0 + r) * N + n0 + tx];
    }
    __syncthreads();
#pragma unroll
    for (int j = 0; j < 4; ++j) {
        int r = ty + j * 8;
        out[(size_t)(n0 + r) * K + k0 + tx] = f2u(tile[tx * 33 + r]);
    }
}

// blocks 0..4095 = W_in (1024x4096); 4096..8191 = Wd (2048x2048); 8192..10239 = W_out (2048x1024)
__global__ __launch_bounds__(256) void transpose3_kernel(const float* __restrict__ W_in,
                                                         u16* __restrict__ Wt_in,
                                                         const float* __restrict__ Wd,
                                                         u16* __restrict__ Wt_d,
                                                         const float* __restrict__ W_out,
                                                         u16* __restrict__ Wt_out) {
    __shared__ float tile[32 * 33];
    int blk = blockIdx.x;
    if (blk < 4096) {
        tr_tile(W_in, Wt_in, 1024, 4096, blk & 127, blk >> 7, tile);
    } else if (blk < 8192) {
        int b2 = blk - 4096;
        tr_tile(Wd, Wt_d, 2048, 2048, b2 & 63, b2 >> 6, tile);
    } else {
        int b3 = blk - 8192;
        tr_tile(W_out, Wt_out, 2048, 1024, b3 & 31, b3 >> 5, tile);
    }
}

// ---------- layernorm over D=1024 + residual pre-copy (out = x) + delta_acc zero ----------
__global__ __launch_bounds__(256) void ln_kernel(const float* __restrict__ x,
                                                 const float* __restrict__ gamma,
                                                 const float* __restrict__ beta,
                                                 u16* __restrict__ h,
                                                 float* __restrict__ out,
                                                 float* __restrict__ delta_acc) {
    int r = blockIdx.x, t = threadIdx.x;
    if (t == 0) delta_acc[r] = 0.f;   // zero accumulator for delta-GEMM atomics
    const float4* xr = (const float4*)(x + (size_t)r * 1024);
    float4 xv = xr[t];
    ((float4*)(out + (size_t)r * 1024))[t] = xv;   // residual base for final atomic GEMM
    float s = xv.x + xv.y + xv.z + xv.w;
    float ss = xv.x * xv.x + xv.y * xv.y + xv.z * xv.z + xv.w * xv.w;
#pragma unroll
    for (int off = 32; off > 0; off >>= 1) {
        s += __shfl_down(s, off, 64);
        ss += __shfl_down(ss, off, 64);
    }
    __shared__ float rs[4], rss[4];
    __shared__ float mu_s, ri_s;
    int wave = t >> 6, lane = t & 63;
    if (lane == 0) { rs[wave] = s; rss[wave] = ss; }
    __syncthreads();
    if (t == 0) {
        float S = rs[0] + rs[1] + rs[2] + rs[3];
        float SS = rss[0] + rss[1] + rss[2] + rss[3];
        float mu = S * (1.f / 1024.f);
        float var = SS * (1.f / 1024.f) - mu * mu;
        mu_s = mu;
        ri_s = rsqrtf(fmaxf(var, 0.f) + 1e-5f);
    }
    __syncthreads();
    float mu = mu_s, ri = ri_s;
    float4 gv = ((const float4*)gamma)[t];
    float4 bv = ((const float4*)beta)[t];
    ushort4 o;
    o.x = f2u((xv.x - mu) * ri * gv.x + bv.x);
    o.y = f2u((xv.y - mu) * ri * gv.y + bv.y);
    o.z = f2u((xv.z - mu) * ri * gv.z + bv.z);
    o.w = f2u((xv.w - mu) * ri * gv.w + bv.w);
    ((ushort4*)(h + (size_t)r * 1024))[t] = o;
}

__device__ __forceinline__ void gl_lds16(const u16* g, u16* l) {
    __builtin_amdgcn_global_load_lds(
        (const __attribute__((address_space(1))) void*)g,
        (__attribute__((address_space(3))) void*)l, 16, 0, 0);
}

// ---------- MFMA GEMM, BK=64, tile 128 x TN (round-4 structure) ----------
// EPI: 0 = store bf16
//      1 = delta fusion: atomicAdd per-row sum of softplus(acc + biasf32[col]) into (float*)out
//      4 = atomicAdd acc into (float*)out (residual pre-initialized; split-K via blockIdx.z)
template <int TN, int EPI>
__global__ __launch_bounds__(256)
void gemm_k(const u16* __restrict__ A, const u16* __restrict__ Bt,
            void* __restrict__ out, const void* __restrict__ aux,
            int M, int N, int K, int Ksub) {
    constexpr int MI = (TN == 128) ? 4 : 2;
    constexpr int BHALF = (TN == 128) ? 4096 : 2048;   // u16 stride between K-halves in Bs
    __shared__ u16 As[128 * 64];
    __shared__ u16 Bs[TN * 64];
    const int tid = threadIdx.x;
    const int wave = tid >> 6, lane = tid & 63;
    const int row0 = blockIdx.y * 128, col0 = blockIdx.x * TN;
    const int koff = blockIdx.z * Ksub;
    const int l16 = lane & 15, q = lane >> 4;
    const int sRow = lane >> 2, sK = (lane & 3) * 8;

    floatx4 acc[MI][4];
#pragma unroll
    for (int i = 0; i < MI; ++i)
#pragma unroll
        for (int j = 0; j < 4; ++j) acc[i][j] = (floatx4){0.f, 0.f, 0.f, 0.f};

    const u16* gA = A + (size_t)(row0 + wave * 32 + sRow) * K + koff + sK;
    u16* lA = As + wave * 1024;   // base within a K-half
    const u16* gB;
    u16* lB;
    if constexpr (TN == 128) {
        gB = Bt + (size_t)(col0 + wave * 32 + sRow) * K + koff + sK;
        lB = Bs + wave * 1024;
    } else {
        gB = Bt + (size_t)(col0 + wave * 16 + sRow) * K + koff + sK;
        lB = Bs + wave * 512;
    }
    const int rowb = (TN == 128) ? (wave >> 1) * 64 : wave * 32;
    const int colb = (TN == 128) ? (wave & 1) * 64 : 0;

    for (int k0 = 0; k0 < Ksub; k0 += 64) {
#pragma unroll
        for (int h = 0; h < 2; ++h) {
            gl_lds16(gA + h * 32, lA + h * 4096);
            gl_lds16(gA + (size_t)16 * K + h * 32, lA + h * 4096 + 512);
            if constexpr (TN == 128) {
                gl_lds16(gB + h * 32, lB + h * 4096);
                gl_lds16(gB + (size_t)16 * K + h * 32, lB + h * 4096 + 512);
            } else {
                gl_lds16(gB + h * 32, lB + h * 2048);
            }
        }
        gA += 64; gB += 64;
        __syncthreads();   // staging visible

#pragma unroll
        for (int h = 0; h < 2; ++h) {
            bf16x8 af[MI], bfr[4];
#pragma unroll
            for (int mi = 0; mi < MI; ++mi)
                af[mi] = *(const bf16x8*)(As + h * 4096 + (rowb + mi * 16 + l16) * 32 + q * 8);
#pragma unroll
            for (int ni = 0; ni < 4; ++ni)
                bfr[ni] = *(const bf16x8*)(Bs + h * BHALF + (colb + ni * 16 + l16) * 32 + q * 8);
#pragma unroll
            for (int mi = 0; mi < MI; ++mi)
#pragma unroll
                for (int ni = 0; ni < 4; ++ni)
                    acc[mi][ni] = __builtin_amdgcn_mfma_f32_16x16x32_bf16(
                        af[mi], bfr[ni], acc[mi][ni], 0, 0, 0);
        }
        __syncthreads();   // compute done before next overwrite
    }

    // epilogue: D row = q*4 + reg, col = l16 (verified m89/m91 mapping)
    const int mB = row0 + rowb;
    const int nB = col0 + colb + l16;
    if constexpr (EPI == 1) {
        float* dacc = (float*)out;
        const float* bias = (const float*)aux;
#pragma unroll
        for (int mi = 0; mi < MI; ++mi) {
#pragma unroll
            for (int rr = 0; rr < 4; ++rr) {
                float s = 0.f;
#pragma unroll
                for (int ni = 0; ni < 4; ++ni) {
                    float t2 = acc[mi][ni][rr] + bias[nB + ni * 16];
                    s += (t2 > 20.f) ? t2 : log1pf(expf(t2));
                }
#pragma unroll
                for (int off = 1; off < 16; off <<= 1)
                    s += __shfl_xor(s, off, 64);
                if (l16 == 0)
                    atomicAdd(&dacc[mB + mi * 16 + q * 4 + rr], s);
            }
        }
    } else if constexpr (EPI == 4) {
        float* C = (float*)out;
#pragma unroll
        for (int mi = 0; mi < MI; ++mi)
#pragma unroll
            for (int ni = 0; ni < 4; ++ni)
#pragma unroll
                for (int rr = 0; rr < 4; ++rr)
                    atomicAdd(&C[(size_t)(mB + mi * 16 + q * 4 + rr) * N + nB + ni * 16],
                              acc[mi][ni][rr]);
    } else {
#pragma unroll
        for (int mi = 0; mi < MI; ++mi)
#pragma unroll
            for (int ni = 0; ni < 4; ++ni)
#pragma unroll
                for (int rr = 0; rr < 4; ++rr)
                    ((u16*)out)[(size_t)(mB + mi * 16 + q * 4 + rr) * N + nB + ni * 16] =
                        f2u(acc[mi][ni][rr]);
    }
}

// ---------- fused depthwise causal conv(K=4) + SiLU + B-dots (shuffle reduction) ----------
__global__ __launch_bounds__(256) void conv_bxda_kernel(const u16* __restrict__ xg,
                                                        const float* __restrict__ conv_w,
                                                        const float* __restrict__ conv_b,
                                                        const float* __restrict__ B_mat,
                                                        u16* __restrict__ xsc,
                                                        float* __restrict__ Bdotn) {
    int r = blockIdx.x;                       // 0..4095
    int l = r & 2047, bb = r >> 11;
    int t = threadIdx.x, d8 = t * 8;
    int wave = t >> 6, lane = t & 63;
    float xs[8];
    {
        float4 b0 = *(const float4*)(conv_b + d8);
        float4 b1 = *(const float4*)(conv_b + d8 + 4);
        xs[0] = b0.x; xs[1] = b0.y; xs[2] = b0.z; xs[3] = b0.w;
        xs[4] = b1.x; xs[5] = b1.y; xs[6] = b1.z; xs[7] = b1.w;
    }
    float w[8][4];
#pragma unroll
    for (int j = 0; j < 8; ++j) {
        float4 wv = *(const float4*)(conv_w + (size_t)(d8 + j) * 4);
        w[j][0] = wv.x; w[j][1] = wv.y; w[j][2] = wv.z; w[j][3] = wv.w;
    }
#pragma unroll
    for (int k = 0; k < 4; ++k) {
        int ls = l + k - 3;
        if (ls >= 0) {
            const u16* row = xg + (size_t)((bb << 11) + ls) * 4096 + d8;
            ushort4 u0 = *(const ushort4*)row;
            ushort4 u1 = *(const ushort4*)(row + 4);
            xs[0] += w[0][k] * u2f(u0.x); xs[1] += w[1][k] * u2f(u0.y);
            xs[2] += w[2][k] * u2f(u0.z); xs[3] += w[3][k] * u2f(u0.w);
            xs[4] += w[4][k] * u2f(u1.x); xs[5] += w[5][k] * u2f(u1.y);
            xs[6] += w[6][k] * u2f(u1.z); xs[7] += w[7][k] * u2f(u1.w);
        }
    }
#pragma unroll
    for (int j = 0; j < 8; ++j) {
        xs[j] = xs[j] / (1.f + expf(-xs[j]));
        xs[j] = u2f(f2u(xs[j]));   // round to bf16 so Bdot matches stored xsc
    }
    ushort4 o0, o1;
    o0.x = f2u(xs[0]); o0.y = f2u(xs[1]); o0.z = f2u(xs[2]); o0.w = f2u(xs[3]);
    o1.x = f2u(xs[4]); o1.y = f2u(xs[5]); o1.z = f2u(xs[6]); o1.w = f2u(xs[7]);
    *(ushort4*)(xsc + (size_t)r * 2048 + d8) = o0;
    *(ushort4*)(xsc + (size_t)r * 2048 + d8 + 4) = o1;

    __shared__ float part[4 * 16];
#pragma unroll
    for (int n = 0; n < 16; ++n) {
        const float* br = B_mat + (size_t)n * 2048 + d8;
        float4 c0 = *(const float4*)br;
        float4 c1 = *(const float4*)(br + 4);
        float a = xs[0] * c0.x + xs[1] * c0.y + xs[2] * c0.z + xs[3] * c0.w
                + xs[4] * c1.x + xs[5] * c1.y + xs[6] * c1.z + xs[7] * c1.w;
#pragma unroll
        for (int off = 1; off < 64; off <<= 1)
            a += __shfl_xor(a, off, 64);
        if (lane == 0) part[wave * 16 + n] = a;
    }
    __syncthreads();
    if (t < 16)
        Bdotn[(size_t)t * 4096 + r] = part[t] + part[16 + t] + part[32 + t] + part[48 + t];
}

// ---------- selective scan: 32 chains, 1 wave each; n-major I/O, LDS-coalesced ----------
__global__ __launch_bounds__(64) void scan_kernel(const float* __restrict__ delta_acc,
                                                  const float* __restrict__ Bdotn,
                                                  const float* __restrict__ A_log,
                                                  float* __restrict__ hsn) {
    int chain = blockIdx.x;                 // 0..31
    int b = chain >> 4, n = chain & 15;
    int j = threadIdx.x;                    // 0..63
    __shared__ float sd[2048], sb[2048];
#pragma unroll
    for (int m = 0; m < 8; ++m) {
        int idx = (m * 64 + j) * 4;
        *(float4*)(sd + idx) = *(const float4*)(delta_acc + b * 2048 + idx);
        *(float4*)(sb + idx) = *(const float4*)(Bdotn + (size_t)n * 4096 + b * 2048 + idx);
    }
    __syncthreads();
    float An = -expf(A_log[n]);
    float a[32], bb[32];
#pragma unroll
    for (int i = 0; i < 32; ++i) {
        float dl = sd[j * 32 + i] * (1.f / 2048.f);
        a[i] = expf(dl * An);
        bb[i] = sb[j * 32 + i] * dl;
    }
    float Aacc = 1.f, Bacc = 0.f;
#pragma unroll
    for (int i = 0; i < 32; ++i) {
        Bacc = a[i] * Bacc + bb[i];
        Aacc = a[i] * Aacc;
    }
#pragma unroll
    for (int d = 1; d < 64; d <<= 1) {
        float Ap = __shfl_up(Aacc, d, 64);
        float Bp = __shfl_up(Bacc, d, 64);
        if (j >= d) {
            Bacc = Aacc * Bp + Bacc;
            Aacc = Aacc * Ap;
        }
    }
    float hstart = __shfl_up(Bacc, 1, 64);
    if (j == 0) hstart = 0.f;
    float h = hstart;
    __syncthreads();
#pragma unroll
    for (int i = 0; i < 32; ++i) {
        h = a[i] * h + bb[i];
        sd[j * 32 + i] = h;
    }
    __syncthreads();
#pragma unroll
    for (int m = 0; m < 8; ++m) {
        int idx = (m * 64 + j) * 4;
        *(float4*)(hsn + (size_t)n * 4096 + b * 2048 + idx) = *(const float4*)(sd + idx);
    }
}

// ---------- ymid = (hs·C_mat[d,:] + D_vec*xsc) * silu(gate), bf16 out ----------
__global__ __launch_bounds__(256) void ymid_kernel(const float* __restrict__ hsn,
                                                   const float* __restrict__ C_mat,
                                                   const float* __restrict__ D_vec,
                                                   const u16* __restrict__ xsc,
                                                   const u16* __restrict__ xg,
                                                   u16* __restrict__ ymid) {
    int r = blockIdx.y;
    int d = blockIdx.x * 256 + threadIdx.x;
    __shared__ float hsv[16];
    if (threadIdx.x < 16) hsv[threadIdx.x] = hsn[(size_t)threadIdx.x * 4096 + r];
    __syncthreads();
    const float* crow = C_mat + (size_t)d * 16;
    float acc = 0.f;
#pragma unroll
    for (int n = 0; n < 16; ++n) acc += hsv[n] * crow[n];
    float xv = u2f(xsc[(size_t)r * 2048 + d]);
    float g = u2f(xg[(size_t)r * 4096 + 2048 + d]);
    float y = acc + D_vec[d] * xv;
    y *= g / (1.f + expf(-g));
    ymid[(size_t)r * 2048 + d] = f2u(y);
}

extern "C" void kernel_launch(void* const* d_in, const int* in_sizes, int n_in,
                              void* d_out, int out_size, void* d_ws, size_t ws_size,
                              hipStream_t stream) {
    (void)in_sizes; (void)n_in;
    const float* x      = (const float*)d_in[0];
    const float* ln_g   = (const float*)d_in[1];
    const float* ln_b   = (const float*)d_in[2];
    const float* W_in   = (const float*)d_in[3];
    const float* conv_w = (const float*)d_in[4];
    const float* conv_b = (const float*)d_in[5];
    const float* A_log  = (const float*)d_in[6];
    const float* B_mat  = (const float*)d_in[7];
    const float* C_mat  = (const float*)d_in[8];
    const float* D_vec  = (const float*)d_in[9];
    const float* Wd     = (const float*)d_in[10];
    const float* bd     = (const float*)d_in[11];
    const float* W_out  = (const float*)d_in[12];
    float* out = (float*)d_out;

    // ---- workspace layout (time-overlaid), ~73 MiB ----
    char* base = (char*)d_ws;
    u16* Wt_in  = (u16*)base;                          // 4096x1024 bf16 (bufA lo)
    u16* h_ln   = (u16*)base + 4096ull * 1024;         // 4096x1024 bf16 (bufA hi)
    u16* ymid   = (u16*)base;                          // 4096x2048 bf16 (reuse bufA post-GEMM1)
    u16* Wt_d   = (u16*)(base + (16ull << 20));        // 2048x2048 bf16 (bufB)
    u16* Wt_out = (u16*)(base + (24ull << 20));        // 1024x2048 bf16 (4 MiB)
    u16* xg     = (u16*)(base + (28ull << 20));        // 4096x4096 bf16 (32 MiB)
    u16* xsc    = (u16*)(base + (60ull << 20));        // 4096x2048 bf16 (16 MiB)
    float* delta_acc = (float*)(base + (76ull << 20)); // 4096 f32
    float* Bdotn = delta_acc + 4096;                   // [16][4096] f32
    float* hsn   = Bdotn + 16 * 4096;                  // [16][4096] f32
    size_t needed = (76ull << 20) + 4096ull * 4 * (1 + 2 * 16);

    if (needed > ws_size) {
        hipMemsetAsync(d_out, 0x7F, (size_t)out_size * 4, stream);  // finite sentinel 3.39e38
        return;
    }

    // 1. all weight transposes (one launch)
    transpose3_kernel<<<10240, 256, 0, stream>>>(W_in, Wt_in, Wd, Wt_d, W_out, Wt_out);
    // 2. layernorm + out=x residual pre-copy + delta_acc zero
    ln_kernel<<<4096, 256, 0, stream>>>(x, ln_g, ln_b, h_ln, out, delta_acc);
    // 3. xg = h @ W_in   128x128 tile, grid 1024
    gemm_k<128, 0><<<dim3(32, 32, 1), 256, 0, stream>>>(h_ln, Wt_in, xg, nullptr,
                                                        4096, 4096, 1024, 1024);
    // 4. fused conv + silu + B-dots (n-major)
    conv_bxda_kernel<<<4096, 256, 0, stream>>>(xg, conv_w, conv_b, B_mat, xsc, Bdotn);
    // 5. delta GEMM (softplus rowsum fused), 128x64 tile, grid 1024
    gemm_k<64, 1><<<dim3(32, 32, 1), 256, 0, stream>>>(xsc, Wt_d, delta_acc, bd,
                                                       4096, 2048, 2048, 2048);
    // 6. selective scan
    scan_kernel<<<32, 64, 0, stream>>>(delta_acc, Bdotn, A_log, hsn);
    // 7. ymid (into bufA; h_ln/Wt_in dead)
    ymid_kernel<<<dim3(8, 4096), 256, 0, stream>>>(hsn, C_mat, D_vec, xsc, xg, ymid);
    // 8. out += ymid @ W_out : 128x64 tile, split-K=2 via atomics, grid 1024
    gemm_k<64, 4><<<dim3(16, 32, 2), 256, 0, stream>>>(ymid, Wt_out, out, nullptr,
                                                       4096, 1024, 2048, 1024);
}